// Round 7
// baseline (1023.218 us; speedup 1.0000x reference)
//
#include <hip/hip_runtime.h>
#include <hip/hip_bf16.h>
#include <math.h>

#define B_TOK 8192
#define D_DIM 1024
#define H_DIM 4096
#define E_NUM 8
#define NPAIR (B_TOK * 2)
#define GRID_P 256  // persistent blocks, 1 per CU (128 KB LDS forces 1/CU)

typedef __bf16 bf16x8 __attribute__((ext_vector_type(8)));
typedef float f32x4 __attribute__((ext_vector_type(4)));
typedef unsigned short us4 __attribute__((ext_vector_type(4)));

__device__ __forceinline__ unsigned short f2bf(float f) {
  union { float f; unsigned u; } v; v.f = f;
  unsigned r = v.u + 0x7FFFu + ((v.u >> 16) & 1u);
  return (unsigned short)(r >> 16);
}

__device__ __forceinline__ void gload16(const void* g, void* l) {
  __builtin_amdgcn_global_load_lds(
      (const __attribute__((address_space(1))) void*)g,
      (__attribute__((address_space(3))) void*)l, 16, 0, 0);
}

#define BARRIER()    asm volatile("s_barrier" ::: "memory")
#define VM8          asm volatile("s_waitcnt vmcnt(8)" ::: "memory")
#define VM4          asm volatile("s_waitcnt vmcnt(4)" ::: "memory")
#define VM0          asm volatile("s_waitcnt vmcnt(0)" ::: "memory")
#define LGKM0        asm volatile("s_waitcnt lgkmcnt(0)" ::: "memory")
#define RF(x) __builtin_amdgcn_readfirstlane(x)

// ---------------- x fp32 -> bf16 ----------------
__global__ void k_convert_x(const float* __restrict__ x, unsigned short* __restrict__ xb) {
  int i = (blockIdx.x * 256 + threadIdx.x) * 4;
  float4 v = *(const float4*)(x + i);
  us4 o;
  o[0] = f2bf(v.x); o[1] = f2bf(v.y); o[2] = f2bf(v.z); o[3] = f2bf(v.w);
  *(us4*)(xb + i) = o;
}

// -------- (E, rows, cols) fp32 -> (E, cols, rows) bf16 --------
__global__ void k_transpose_bf16(const float* __restrict__ in, unsigned short* __restrict__ out,
                                 int rows, int cols) {
  __shared__ float t[32][33];
  const float* ine = in + (size_t)blockIdx.z * rows * cols;
  unsigned short* oute = out + (size_t)blockIdx.z * rows * cols;
  int c0 = blockIdx.x * 32, r0 = blockIdx.y * 32;
  int tx = threadIdx.x, ty = threadIdx.y;
#pragma unroll
  for (int j = 0; j < 32; j += 8)
    t[ty + j][tx] = ine[(size_t)(r0 + ty + j) * cols + c0 + tx];
  __syncthreads();
#pragma unroll
  for (int j = 0; j < 32; j += 8)
    oute[(size_t)(c0 + ty + j) * rows + r0 + tx] = f2bf(t[tx][ty + j]);
}

// ---------------- router: logits, top-2, softmax ----------------
__global__ void k_router(const float* __restrict__ x, const float* __restrict__ wg,
                         const float* __restrict__ bg, int* __restrict__ tidx,
                         float* __restrict__ tgate, int* __restrict__ cnt) {
  int wid = threadIdx.x >> 6, lane = threadIdx.x & 63;
  int t = blockIdx.x * 4 + wid;
  float acc[E_NUM];
#pragma unroll
  for (int e = 0; e < E_NUM; e++) acc[e] = 0.f;
  const float* xr = x + (size_t)t * D_DIM;
  for (int i = lane; i < D_DIM; i += 64) {
    float xv = xr[i];
#pragma unroll
    for (int e = 0; e < E_NUM; e++) acc[e] += xv * wg[e * D_DIM + i];
  }
#pragma unroll
  for (int e = 0; e < E_NUM; e++) {
#pragma unroll
    for (int off = 32; off; off >>= 1) acc[e] += __shfl_xor(acc[e], off);
  }
  if (lane == 0) {
    float v[E_NUM];
#pragma unroll
    for (int e = 0; e < E_NUM; e++) v[e] = acc[e] + bg[e];
    int i0 = 0; float v0 = v[0];
#pragma unroll
    for (int e = 1; e < E_NUM; e++) if (v[e] > v0) { v0 = v[e]; i0 = e; }
    int i1 = -1; float v1 = -1e30f;
#pragma unroll
    for (int e = 0; e < E_NUM; e++) if (e != i0 && v[e] > v1) { v1 = v[e]; i1 = e; }
    float g0 = 1.f / (1.f + expf(v1 - v0));
    float g1 = 1.f - g0;
    tidx[2 * t] = i0; tidx[2 * t + 1] = i1;
    tgate[2 * t] = g0; tgate[2 * t + 1] = g1;
    atomicAdd(cnt + i0, 1);
    atomicAdd(cnt + i1, 1);
  }
}

// meta: cnt[8] | eoff[9] | cursor[8] | toff1[9] | toff2[9]
__global__ void k_prefix(int* __restrict__ meta) {
  if (threadIdx.x == 0) {
    int* cnt = meta;
    int* eoff = meta + 8;
    int* cursor = meta + 17;
    int* toff1 = meta + 25;
    int* toff2 = meta + 34;
    int a = 0, t1 = 0, t2 = 0;
    for (int e = 0; e < E_NUM; e++) {
      eoff[e] = a; cursor[e] = a; a += cnt[e];
      toff1[e] = t1; toff2[e] = t2;
      int mc = (cnt[e] + 255) >> 8;  // ceil(cnt/256)
      t1 += mc * (H_DIM / 256);       // NT1=16, KSPLIT1=1
      t2 += mc * (D_DIM / 256) * 2;   // NT2=4,  KSPLIT2=2
    }
    eoff[E_NUM] = a; toff1[E_NUM] = t1; toff2[E_NUM] = t2;
  }
}

__global__ void k_scatter(const int* __restrict__ tidx, const float* __restrict__ tgate,
                          int* __restrict__ cursor, int* __restrict__ ptok,
                          float* __restrict__ pgate) {
  int t = blockIdx.x * 256 + threadIdx.x;
#pragma unroll
  for (int k = 0; k < 2; k++) {
    int e = tidx[2 * t + k];
    int p = atomicAdd(cursor + e, 1);
    ptok[p] = t;
    pgate[p] = tgate[2 * t + k];
  }
}

// ---- persistent grouped GEMM, 256x256 tile, BK=32, depth-4 pipeline -------
// Grid = 256 blocks (1/CU). Block b processes compacted tiles b, b+256, ...
// LDS: 4 bufs x (A,B) x [256 rows][32 bf16]; seg-swizzle slot[row][s] =
// data[row][s ^ ((row>>1)&3)] via pre-swizzled global source (R5: 0 conflicts).
// Pipeline: 3 K-steps staged ahead; steady step: vmcnt(8) -> barrier ->
// frag ds_reads -> lgkm0 -> barrier (WAR) -> STAGE(step+3) -> 32 MFMA.
// Each wave's own vmcnt-before-barrier + barrier join makes all waves'
// stages for the buffer visible before any wave reads it.
// MODE 1: A = xb gathered via ptok, out = relu(A@B^T + b1) -> Hbuf (bf16)
// MODE 2: A = Hbuf rows direct, split-K, out = (A@B^T + b2*(kc==0))*g atomic
template <int KDIM, int NDIM, int MODE, int KSPLIT>
__global__ __launch_bounds__(512, 1) void k_gemm(
    const unsigned short* __restrict__ A, const unsigned short* __restrict__ Bt,
    const float* __restrict__ bias, const int* __restrict__ meta,
    const int* __restrict__ ptok, const float* __restrict__ pgate,
    unsigned short* __restrict__ Hout, float* __restrict__ Out) {
  constexpr int NT = NDIM / 256;
  constexpr int KLEN = KDIM / KSPLIT;
  constexpr int NKT = KLEN / 32;      // K-steps per tile (mult of 4, >= 8)
  const int* eoff = meta + 8;
  const int* toff = (MODE == 1) ? (meta + 25) : (meta + 34);

  __shared__ unsigned short lds[4][2][256 * 32];  // 128 KiB

  int tid = threadIdx.x;
  int w = tid >> 6, lane = tid & 63;
  int wm = w >> 2, wn = w & 3;  // 2x4 wave grid; per-wave output 128x64

  int sseg = (lane & 3) ^ ((lane >> 3) & 3);          // staging src seg
  int segp = (lane >> 4) ^ ((lane >> 1) & 3);         // frag read seg

  int tf[E_NUM + 1];
#pragma unroll
  for (int q = 0; q <= E_NUM; q++) tf[q] = RF(toff[q]);
  int T = tf[E_NUM];
  int bid = blockIdx.x;

#pragma unroll 1
  for (int i = bid; i < T; i += GRID_P) {
    // ---- decode compacted tile index ----
    int e = 0;
#pragma unroll
    for (int q = 1; q < E_NUM; q++) e += (i >= tf[q]);
    int r = i - tf[e];
    int mt = r / (NT * KSPLIT);
    int r2 = r - mt * (NT * KSPLIT);
    int nt = r2 / KSPLIT;
    int kc = r2 - nt * KSPLIT;
    int off = RF(eoff[e]);
    int cnte = RF(eoff[e + 1]) - off;
    int m0 = mt * 256;            // m0 < cnte guaranteed by construction
    int kbase = kc * KLEN;

    // ---- staging sources (R5 geometry): chunk q=w*2+c rows q*16..+15 ----
    const unsigned short* aSrc[2];
    const unsigned short* bSrc[2];
#pragma unroll
    for (int c = 0; c < 2; c++) {
      int q = w * 2 + c;
      int lrow = q * 16 + (lane >> 2);
      int arow = m0 + lrow;
      int ar = (arow < cnte) ? arow : (cnte - 1);
      size_t grow;
      if (MODE == 1) grow = (size_t)ptok[off + ar];
      else grow = (size_t)(off + ar);
      aSrc[c] = A + grow * KDIM + kbase + sseg * 8;
      int nrow = nt * 256 + q * 16 + (lane >> 2);
      bSrc[c] = Bt + (size_t)e * NDIM * KDIM + (size_t)nrow * KDIM + kbase + sseg * 8;
    }

    f32x4 acc[8][4] = {};

#define STAGE(buf, k0)                                          \
  {                                                             \
    _Pragma("unroll")                                           \
    for (int c = 0; c < 2; c++) {                               \
      int q = w * 2 + c;                                        \
      gload16(aSrc[c] + (k0), &lds[buf][0][q * 512]);           \
      gload16(bSrc[c] + (k0), &lds[buf][1][q * 512]);           \
    }                                                           \
  }
#define NOSTG ((void)0)

#define STEP(buf, WAITC, STGC)                                              \
  {                                                                         \
    WAITC; BARRIER();                                                       \
    bf16x8 aF[8], bF[4];                                                    \
    _Pragma("unroll")                                                       \
    for (int m = 0; m < 8; m++) {                                           \
      int row = wm * 128 + m * 16 + (lane & 15);                            \
      aF[m] = *(const bf16x8*)&lds[buf][0][row * 32 + segp * 8];            \
    }                                                                       \
    _Pragma("unroll")                                                       \
    for (int n = 0; n < 4; n++) {                                           \
      int row = wn * 64 + n * 16 + (lane & 15);                             \
      bF[n] = *(const bf16x8*)&lds[buf][1][row * 32 + segp * 8];            \
    }                                                                       \
    LGKM0; BARRIER();                                                       \
    STGC;                                                                   \
    __builtin_amdgcn_s_setprio(1);                                          \
    _Pragma("unroll")                                                       \
    for (int m = 0; m < 8; m++)                                             \
      _Pragma("unroll")                                                     \
      for (int n = 0; n < 4; n++)                                           \
        acc[m][n] =                                                         \
            __builtin_amdgcn_mfma_f32_16x16x32_bf16(aF[m], bF[n], acc[m][n], 0, 0, 0); \
    __builtin_amdgcn_s_setprio(0);                                          \
  }

    // prologue: stage K-steps 0,1,2 into bufs 0,1,2 (12 loads in flight)
    STAGE(0, 0); STAGE(1, 32); STAGE(2, 64);

#pragma unroll 1
    for (int kt = 0; kt <= NKT - 8; kt += 4) {
      STEP(0, VM8, STAGE(3, (kt + 3) * 32));
      STEP(1, VM8, STAGE(0, (kt + 4) * 32));
      STEP(2, VM8, STAGE(1, (kt + 5) * 32));
      STEP(3, VM8, STAGE(2, (kt + 6) * 32));
    }
    // final group (kt = NKT-4): one last stage, then drain
    STEP(0, VM8, STAGE(3, (NKT - 1) * 32));
    STEP(1, VM8, NOSTG);
    STEP(2, VM4, NOSTG);
    STEP(3, VM0, NOSTG);

#undef STAGE
#undef NOSTG
#undef STEP

    // ---- epilogue: C/D map col=lane&15, row=(lane>>4)*4+rr ----
#pragma unroll
    for (int m = 0; m < 8; m++) {
      int lrowb = wm * 128 + m * 16 + (lane >> 4) * 4;
#pragma unroll
      for (int rr = 0; rr < 4; rr++) {
        int arow = m0 + lrowb + rr;
        if (arow < cnte) {
          if constexpr (MODE == 1) {
            size_t rowbase = (size_t)(off + arow) * NDIM;
#pragma unroll
            for (int n = 0; n < 4; n++) {
              int col = nt * 256 + wn * 64 + n * 16 + (lane & 15);
              float v = acc[m][n][rr] + bias[e * NDIM + col];
              v = v > 0.f ? v : 0.f;
              Hout[rowbase + col] = f2bf(v);
            }
          } else {
            int tok = ptok[off + arow];
            float g = pgate[off + arow];
#pragma unroll
            for (int n = 0; n < 4; n++) {
              int col = nt * 256 + wn * 64 + n * 16 + (lane & 15);
              float b = (kc == 0) ? bias[e * NDIM + col] : 0.f;
              float v = (acc[m][n][rr] + b) * g;
              atomicAdd(Out + (size_t)tok * D_DIM + col, v);
            }
          }
        }
      }
    }
  }  // tile loop
}

extern "C" void kernel_launch(void* const* d_in, const int* in_sizes, int n_in,
                              void* d_out, int out_size, void* d_ws, size_t ws_size,
                              hipStream_t stream) {
  const float* x  = (const float*)d_in[0];
  const float* wg = (const float*)d_in[1];
  const float* bg = (const float*)d_in[2];
  const float* w1 = (const float*)d_in[3];
  const float* b1 = (const float*)d_in[4];
  const float* w2 = (const float*)d_in[5];
  const float* b2 = (const float*)d_in[6];
  float* out = (float*)d_out;

  char* ws = (char*)d_ws;
  unsigned short* xb = (unsigned short*)ws;   ws += (size_t)B_TOK * D_DIM * 2;
  unsigned short* w1t = (unsigned short*)ws;  ws += (size_t)E_NUM * D_DIM * H_DIM * 2;
  unsigned short* w2t = (unsigned short*)ws;  ws += (size_t)E_NUM * D_DIM * H_DIM * 2;
  unsigned short* Hbuf = (unsigned short*)ws; ws += (size_t)NPAIR * H_DIM * 2;
  int* tidx = (int*)ws;    ws += (size_t)NPAIR * 4;
  float* tgate = (float*)ws; ws += (size_t)NPAIR * 4;
  int* ptok = (int*)ws;    ws += (size_t)NPAIR * 4;
  float* pgate = (float*)ws; ws += (size_t)NPAIR * 4;
  int* meta = (int*)ws;  // cnt[8] | eoff[9] | cursor[8] | toff1[9] | toff2[9]
  int* cnt = meta;
  int* cursor = meta + 17;

  hipMemsetAsync(meta, 0, 64 * sizeof(int), stream);
  hipMemsetAsync(out, 0, (size_t)out_size * sizeof(float), stream);

  k_convert_x<<<(B_TOK * D_DIM) / 1024, 256, 0, stream>>>(x, xb);
  dim3 tb(32, 8);
  k_transpose_bf16<<<dim3(H_DIM / 32, D_DIM / 32, E_NUM), tb, 0, stream>>>(w1, w1t, D_DIM, H_DIM);
  k_transpose_bf16<<<dim3(D_DIM / 32, H_DIM / 32, E_NUM), tb, 0, stream>>>(w2, w2t, H_DIM, D_DIM);
  k_router<<<B_TOK / 4, 256, 0, stream>>>(x, wg, bg, tidx, tgate, cnt);
  k_prefix<<<1, 64, 0, stream>>>(meta);
  k_scatter<<<B_TOK / 256, 256, 0, stream>>>(tidx, tgate, cursor, ptok, pgate);
  k_gemm<D_DIM, H_DIM, 1, 1><<<GRID_P, 512, 0, stream>>>(
      xb, w1t, b1, meta, ptok, pgate, Hbuf, nullptr);
  k_gemm<H_DIM, D_DIM, 2, 2><<<GRID_P, 512, 0, stream>>>(
      Hbuf, w2t, b2, meta, ptok, pgate, nullptr, out);
}

// Round 8
// 834.604 us; speedup vs baseline: 1.2260x; 1.2260x over previous
//
#include <hip/hip_runtime.h>
#include <hip/hip_bf16.h>
#include <math.h>

#define B_TOK 8192
#define D_DIM 1024
#define H_DIM 4096
#define E_NUM 8
#define NPAIR (B_TOK * 2)

typedef __bf16 bf16x8 __attribute__((ext_vector_type(8)));
typedef float f32x4 __attribute__((ext_vector_type(4)));
typedef unsigned short us4 __attribute__((ext_vector_type(4)));

__device__ __forceinline__ unsigned short f2bf(float f) {
  union { float f; unsigned u; } v; v.f = f;
  unsigned r = v.u + 0x7FFFu + ((v.u >> 16) & 1u);
  return (unsigned short)(r >> 16);
}

__device__ __forceinline__ void gload16(const void* g, void* l) {
  __builtin_amdgcn_global_load_lds(
      (const __attribute__((address_space(1))) void*)g,
      (__attribute__((address_space(3))) void*)l, 16, 0, 0);
}

#define BARRIER()    asm volatile("s_barrier" ::: "memory")
#define VM4          asm volatile("s_waitcnt vmcnt(4)" ::: "memory")
#define VM0          asm volatile("s_waitcnt vmcnt(0)" ::: "memory")
#define LGKM0        asm volatile("s_waitcnt lgkmcnt(0)" ::: "memory")

// ---------------- x fp32 -> bf16 ----------------
__global__ void k_convert_x(const float* __restrict__ x, unsigned short* __restrict__ xb) {
  int i = (blockIdx.x * 256 + threadIdx.x) * 4;
  float4 v = *(const float4*)(x + i);
  us4 o;
  o[0] = f2bf(v.x); o[1] = f2bf(v.y); o[2] = f2bf(v.z); o[3] = f2bf(v.w);
  *(us4*)(xb + i) = o;
}

// -------- (E, rows, cols) fp32 -> (E, cols, rows) bf16 --------
__global__ void k_transpose_bf16(const float* __restrict__ in, unsigned short* __restrict__ out,
                                 int rows, int cols) {
  __shared__ float t[32][33];
  const float* ine = in + (size_t)blockIdx.z * rows * cols;
  unsigned short* oute = out + (size_t)blockIdx.z * rows * cols;
  int c0 = blockIdx.x * 32, r0 = blockIdx.y * 32;
  int tx = threadIdx.x, ty = threadIdx.y;
#pragma unroll
  for (int j = 0; j < 32; j += 8)
    t[ty + j][tx] = ine[(size_t)(r0 + ty + j) * cols + c0 + tx];
  __syncthreads();
#pragma unroll
  for (int j = 0; j < 32; j += 8)
    oute[(size_t)(c0 + ty + j) * rows + r0 + tx] = f2bf(t[tx][ty + j]);
}

// ---------------- router: logits, top-2, softmax ----------------
__global__ void k_router(const float* __restrict__ x, const float* __restrict__ wg,
                         const float* __restrict__ bg, int* __restrict__ tidx,
                         float* __restrict__ tgate, int* __restrict__ cnt) {
  int wid = threadIdx.x >> 6, lane = threadIdx.x & 63;
  int t = blockIdx.x * 4 + wid;
  float acc[E_NUM];
#pragma unroll
  for (int e = 0; e < E_NUM; e++) acc[e] = 0.f;
  const float* xr = x + (size_t)t * D_DIM;
  for (int i = lane; i < D_DIM; i += 64) {
    float xv = xr[i];
#pragma unroll
    for (int e = 0; e < E_NUM; e++) acc[e] += xv * wg[e * D_DIM + i];
  }
#pragma unroll
  for (int e = 0; e < E_NUM; e++) {
#pragma unroll
    for (int off = 32; off; off >>= 1) acc[e] += __shfl_xor(acc[e], off);
  }
  if (lane == 0) {
    float v[E_NUM];
#pragma unroll
    for (int e = 0; e < E_NUM; e++) v[e] = acc[e] + bg[e];
    int i0 = 0; float v0 = v[0];
#pragma unroll
    for (int e = 1; e < E_NUM; e++) if (v[e] > v0) { v0 = v[e]; i0 = e; }
    int i1 = -1; float v1 = -1e30f;
#pragma unroll
    for (int e = 0; e < E_NUM; e++) if (e != i0 && v[e] > v1) { v1 = v[e]; i1 = e; }
    float g0 = 1.f / (1.f + expf(v1 - v0));
    float g1 = 1.f - g0;
    tidx[2 * t] = i0; tidx[2 * t + 1] = i1;
    tgate[2 * t] = g0; tgate[2 * t + 1] = g1;
    atomicAdd(cnt + i0, 1);
    atomicAdd(cnt + i1, 1);
  }
}

__global__ void k_prefix(const int* __restrict__ cnt, int* __restrict__ eoff,
                         int* __restrict__ cursor) {
  if (threadIdx.x == 0) {
    int a = 0;
    for (int e = 0; e < E_NUM; e++) { eoff[e] = a; cursor[e] = a; a += cnt[e]; }
    eoff[E_NUM] = a;
  }
}

__global__ void k_scatter(const int* __restrict__ tidx, const float* __restrict__ tgate,
                          int* __restrict__ cursor, int* __restrict__ ptok,
                          float* __restrict__ pgate) {
  int t = blockIdx.x * 256 + threadIdx.x;
#pragma unroll
  for (int k = 0; k < 2; k++) {
    int e = tidx[2 * t + k];
    int p = atomicAdd(cursor + e, 1);
    ptok[p] = t;
    pgate[p] = tgate[2 * t + k];
  }
}

// ---- grouped GEMM, 128x128 tile, BK=32, dbuf + counted vmcnt, 4-5 blk/CU ---
// 4 waves (256 thr), per-wave 64x64 output (acc[4][4]); LDS 32 KB:
// [buf][A/B][128 rows][32 bf16], 64B rows of 4x16B segs, seg-swizzled
// slot[row][s] = data[row][s ^ ((row>>1)&3)] via pre-swizzled global source
// (R3/R5: measured 0 bank conflicts). Schedule per K-step (R5, proven):
// vmcnt(4) -> barrier -> 8 frag ds_reads -> lgkm0 -> barrier (WAR) ->
// STAGE(t+2) -> setprio(1) 16 MFMA setprio(0). Cross-block TLP (4-5 blocks
// co-resident) hides the serial phases (m114 mechanism; R1 existence proof).
// MODE 1: A = xb gathered via ptok, out = relu(A@B^T + b1) -> Hbuf (bf16)
// MODE 2: A = Hbuf rows direct,   out = (A@B^T + b2)*gate atomicAdd-> Out
template <int KDIM, int NDIM, int MODE>
__global__ __launch_bounds__(256, 2) void k_gemm(
    const unsigned short* __restrict__ A, const unsigned short* __restrict__ Bt,
    const float* __restrict__ bias, const int* __restrict__ eoff,
    const int* __restrict__ ptok, const float* __restrict__ pgate,
    unsigned short* __restrict__ Hout, float* __restrict__ Out) {
  constexpr int NT = NDIM / 128;
  constexpr int MT_MAX = NPAIR / 128;
  int nwg = gridDim.x;
  int bid = blockIdx.x;
  int tile = (bid & 7) * (nwg >> 3) + (bid >> 3);  // XCD chunk swizzle (nwg%8==0)
  int e = tile / (MT_MAX * NT);
  int rem = tile - e * (MT_MAX * NT);
  int mt = rem / NT;
  int nt = rem - mt * NT;
  int off = eoff[e];
  int cnt = eoff[e + 1] - off;
  int m0 = mt * 128;
  if (m0 >= cnt) return;

  __shared__ unsigned short lds[2][2][128 * 32];  // 32 KB

  int tid = threadIdx.x;
  int w = tid >> 6, lane = tid & 63;
  int wm = w >> 1, wn = w & 1;  // 2x2 wave grid; per-wave output 64x64

  // staging: chunk q = w*2+c covers rows q*16..q*16+15; lane -> row
  // q*16+(lane>>2), slot seg (lane&3); LDS offset q*512 + lane*8 shorts.
  // Pre-swizzled global seg: (lane&3) ^ ((row>>1)&3) = (lane&3)^((lane>>3)&3).
  int sseg = (lane & 3) ^ ((lane >> 3) & 3);
  const unsigned short* aSrc[2];
  const unsigned short* bSrc[2];
#pragma unroll
  for (int c = 0; c < 2; c++) {
    int q = w * 2 + c;
    int lrow = q * 16 + (lane >> 2);
    int arow = m0 + lrow;
    int ar = (arow < cnt) ? arow : (cnt - 1);
    size_t grow;
    if (MODE == 1) grow = (size_t)ptok[off + ar];
    else grow = (size_t)(off + ar);
    aSrc[c] = A + grow * KDIM + sseg * 8;
    int nrow = nt * 128 + q * 16 + (lane >> 2);
    bSrc[c] = Bt + (size_t)e * NDIM * KDIM + (size_t)nrow * KDIM + sseg * 8;
  }

  // frag reads: row = base + (lane&15); wanted seg = lane>>4;
  // slot seg' = (lane>>4) ^ ((row>>1)&3) = (lane>>4) ^ ((lane>>1)&3).
  int segp = (lane >> 4) ^ ((lane >> 1) & 3);
  f32x4 acc[4][4] = {};

#define STAGE(buf, k0)                                          \
  {                                                             \
    _Pragma("unroll")                                           \
    for (int c = 0; c < 2; c++) {                               \
      int q = w * 2 + c;                                        \
      gload16(aSrc[c] + (k0), &lds[buf][0][q * 512]);           \
      gload16(bSrc[c] + (k0), &lds[buf][1][q * 512]);           \
    }                                                           \
  }

#define FRAG_READ(buf)                                                      \
    _Pragma("unroll")                                                       \
    for (int m = 0; m < 4; m++) {                                           \
      int row = wm * 64 + m * 16 + (lane & 15);                             \
      aF[m] = *(const bf16x8*)&lds[buf][0][row * 32 + segp * 8];            \
    }                                                                       \
    _Pragma("unroll")                                                       \
    for (int n = 0; n < 4; n++) {                                           \
      int row = wn * 64 + n * 16 + (lane & 15);                             \
      bF[n] = *(const bf16x8*)&lds[buf][1][row * 32 + segp * 8];            \
    }

#define MFMA_ALL()                                                          \
    __builtin_amdgcn_s_setprio(1);                                          \
    _Pragma("unroll")                                                       \
    for (int m = 0; m < 4; m++)                                             \
      _Pragma("unroll")                                                     \
      for (int n = 0; n < 4; n++)                                           \
        acc[m][n] =                                                         \
            __builtin_amdgcn_mfma_f32_16x16x32_bf16(aF[m], bF[n], acc[m][n], 0, 0, 0); \
    __builtin_amdgcn_s_setprio(0);

  // prologue: 2 K-steps in flight (4 loads each per thread)
  STAGE(0, 0);
  STAGE(1, 32);

#pragma unroll 1
  for (int k0 = 0; k0 < KDIM - 64; k0 += 64) {
    {
      VM4; BARRIER();              // buf0's 4 loads landed (buf1's in flight)
      bf16x8 aF[4], bF[4];
      FRAG_READ(0);
      LGKM0; BARRIER();            // all waves done reading buf0 (WAR)
      STAGE(0, k0 + 64);           // refill buf0 with step t+2
      MFMA_ALL();
    }
    {
      VM4; BARRIER();
      bf16x8 aF[4], bF[4];
      FRAG_READ(1);
      LGKM0; BARRIER();
      STAGE(1, k0 + 96);
      MFMA_ALL();
    }
  }
  // tail: last two steps, no further staging
  {
    VM4; BARRIER();
    bf16x8 aF[4], bF[4];
    FRAG_READ(0);
    MFMA_ALL();
  }
  {
    VM0; BARRIER();
    bf16x8 aF[4], bF[4];
    FRAG_READ(1);
    MFMA_ALL();
  }

#undef STAGE
#undef FRAG_READ
#undef MFMA_ALL

  // epilogue: C/D map col=lane&15, row=(lane>>4)*4+r
#pragma unroll
  for (int m = 0; m < 4; m++) {
    int lrowb = wm * 64 + m * 16 + (lane >> 4) * 4;
#pragma unroll
    for (int r = 0; r < 4; r++) {
      int arow = m0 + lrowb + r;
      if (arow < cnt) {
        if constexpr (MODE == 1) {
          size_t rowbase = (size_t)(off + arow) * NDIM;
#pragma unroll
          for (int n = 0; n < 4; n++) {
            int col = nt * 128 + wn * 64 + n * 16 + (lane & 15);
            float v = acc[m][n][r] + bias[e * NDIM + col];
            v = v > 0.f ? v : 0.f;
            Hout[rowbase + col] = f2bf(v);
          }
        } else {
          int tok = ptok[off + arow];
          float g = pgate[off + arow];
#pragma unroll
          for (int n = 0; n < 4; n++) {
            int col = nt * 128 + wn * 64 + n * 16 + (lane & 15);
            float v = (acc[m][n][r] + bias[e * NDIM + col]) * g;
            atomicAdd(Out + (size_t)tok * D_DIM + col, v);
          }
        }
      }
    }
  }
}

extern "C" void kernel_launch(void* const* d_in, const int* in_sizes, int n_in,
                              void* d_out, int out_size, void* d_ws, size_t ws_size,
                              hipStream_t stream) {
  const float* x  = (const float*)d_in[0];
  const float* wg = (const float*)d_in[1];
  const float* bg = (const float*)d_in[2];
  const float* w1 = (const float*)d_in[3];
  const float* b1 = (const float*)d_in[4];
  const float* w2 = (const float*)d_in[5];
  const float* b2 = (const float*)d_in[6];
  float* out = (float*)d_out;

  char* ws = (char*)d_ws;
  unsigned short* xb = (unsigned short*)ws;   ws += (size_t)B_TOK * D_DIM * 2;
  unsigned short* w1t = (unsigned short*)ws;  ws += (size_t)E_NUM * D_DIM * H_DIM * 2;
  unsigned short* w2t = (unsigned short*)ws;  ws += (size_t)E_NUM * D_DIM * H_DIM * 2;
  unsigned short* Hbuf = (unsigned short*)ws; ws += (size_t)NPAIR * H_DIM * 2;
  int* tidx = (int*)ws;    ws += (size_t)NPAIR * 4;
  float* tgate = (float*)ws; ws += (size_t)NPAIR * 4;
  int* ptok = (int*)ws;    ws += (size_t)NPAIR * 4;
  float* pgate = (float*)ws; ws += (size_t)NPAIR * 4;
  int* meta = (int*)ws;  // cnt[8] | eoff[9] | cursor[8]
  int* cnt = meta;
  int* eoff = meta + 8;
  int* cursor = meta + 17;

  hipMemsetAsync(meta, 0, 32 * sizeof(int), stream);
  hipMemsetAsync(out, 0, (size_t)out_size * sizeof(float), stream);

  k_convert_x<<<(B_TOK * D_DIM) / 1024, 256, 0, stream>>>(x, xb);
  dim3 tb(32, 8);
  k_transpose_bf16<<<dim3(H_DIM / 32, D_DIM / 32, E_NUM), tb, 0, stream>>>(w1, w1t, D_DIM, H_DIM);
  k_transpose_bf16<<<dim3(D_DIM / 32, H_DIM / 32, E_NUM), tb, 0, stream>>>(w2, w2t, H_DIM, D_DIM);
  k_router<<<B_TOK / 4, 256, 0, stream>>>(x, wg, bg, tidx, tgate, cnt);
  k_prefix<<<1, 64, 0, stream>>>(cnt, eoff, cursor);
  k_scatter<<<B_TOK / 256, 256, 0, stream>>>(tidx, tgate, cursor, ptok, pgate);
  k_gemm<D_DIM, H_DIM, 1><<<E_NUM * (NPAIR / 128) * (H_DIM / 128), 256, 0, stream>>>(
      xb, w1t, b1, eoff, ptok, pgate, Hbuf, nullptr);
  k_gemm<H_DIM, D_DIM, 2><<<E_NUM * (NPAIR / 128) * (D_DIM / 128), 256, 0, stream>>>(
      Hbuf, w2t, b2, eoff, ptok, pgate, nullptr, out);
}

// Round 9
// 826.753 us; speedup vs baseline: 1.2376x; 1.0095x over previous
//
#include <hip/hip_runtime.h>
#include <hip/hip_bf16.h>
#include <math.h>

#define B_TOK 8192
#define D_DIM 1024
#define H_DIM 4096
#define E_NUM 8
#define NPAIR (B_TOK * 2)

typedef __bf16 bf16x8 __attribute__((ext_vector_type(8)));
typedef float f32x4 __attribute__((ext_vector_type(4)));
typedef unsigned short us4 __attribute__((ext_vector_type(4)));

__device__ __forceinline__ unsigned short f2bf(float f) {
  union { float f; unsigned u; } v; v.f = f;
  unsigned r = v.u + 0x7FFFu + ((v.u >> 16) & 1u);
  return (unsigned short)(r >> 16);
}

__device__ __forceinline__ void gload16(const void* g, void* l) {
  __builtin_amdgcn_global_load_lds(
      (const __attribute__((address_space(1))) void*)g,
      (__attribute__((address_space(3))) void*)l, 16, 0, 0);
}

#define BARRIER()    asm volatile("s_barrier" ::: "memory")
#define VM8          asm volatile("s_waitcnt vmcnt(8)" ::: "memory")
#define VM4          asm volatile("s_waitcnt vmcnt(4)" ::: "memory")
#define VM0          asm volatile("s_waitcnt vmcnt(0)" ::: "memory")
#define LGKM0        asm volatile("s_waitcnt lgkmcnt(0)" ::: "memory")

// ---------------- x fp32 -> bf16 ----------------
__global__ void k_convert_x(const float* __restrict__ x, unsigned short* __restrict__ xb) {
  int i = (blockIdx.x * 256 + threadIdx.x) * 4;
  float4 v = *(const float4*)(x + i);
  us4 o;
  o[0] = f2bf(v.x); o[1] = f2bf(v.y); o[2] = f2bf(v.z); o[3] = f2bf(v.w);
  *(us4*)(xb + i) = o;
}

// ---- fused weight prep: w1 (E,D,H) -> w1t (E,H,D) bf16; w2 (E,H,D) -> w2t (E,D,H) ----
// 1D grid of 2*8*4096 blocks; 4096 32x32 tiles per expert per tensor.
__global__ void k_prep_w(const float* __restrict__ w1, const float* __restrict__ w2,
                         unsigned short* __restrict__ w1t, unsigned short* __restrict__ w2t) {
  __shared__ float t[32][33];
  int b = blockIdx.x;
  int which = b >> 15;          // 0: w1, 1: w2
  int lb = b & 32767;
  int e = lb >> 12;
  int local = lb & 4095;
  int rows = which ? H_DIM : D_DIM;   // input rows
  int cols = which ? D_DIM : H_DIM;   // input cols
  int xt = which ? (local & 31) : (local & 127);
  int yt = which ? (local >> 5) : (local >> 7);
  const float* ine = (which ? w2 : w1) + (size_t)e * D_DIM * H_DIM;
  unsigned short* oute = (which ? w2t : w1t) + (size_t)e * D_DIM * H_DIM;
  int c0 = xt * 32, r0 = yt * 32;
  int tx = threadIdx.x, ty = threadIdx.y;
#pragma unroll
  for (int j = 0; j < 32; j += 8)
    t[ty + j][tx] = ine[(size_t)(r0 + ty + j) * cols + c0 + tx];
  __syncthreads();
#pragma unroll
  for (int j = 0; j < 32; j += 8)
    oute[(size_t)(c0 + ty + j) * rows + r0 + tx] = f2bf(t[tx][ty + j]);
}

// ---------------- router: logits, top-2, softmax ----------------
__global__ void k_router(const float* __restrict__ x, const float* __restrict__ wg,
                         const float* __restrict__ bg, int* __restrict__ tidx,
                         float* __restrict__ tgate, int* __restrict__ cnt) {
  int wid = threadIdx.x >> 6, lane = threadIdx.x & 63;
  int t = blockIdx.x * 4 + wid;
  float acc[E_NUM];
#pragma unroll
  for (int e = 0; e < E_NUM; e++) acc[e] = 0.f;
  const float* xr = x + (size_t)t * D_DIM;
  for (int i = lane; i < D_DIM; i += 64) {
    float xv = xr[i];
#pragma unroll
    for (int e = 0; e < E_NUM; e++) acc[e] += xv * wg[e * D_DIM + i];
  }
#pragma unroll
  for (int e = 0; e < E_NUM; e++) {
#pragma unroll
    for (int off = 32; off; off >>= 1) acc[e] += __shfl_xor(acc[e], off);
  }
  if (lane == 0) {
    float v[E_NUM];
#pragma unroll
    for (int e = 0; e < E_NUM; e++) v[e] = acc[e] + bg[e];
    int i0 = 0; float v0 = v[0];
#pragma unroll
    for (int e = 1; e < E_NUM; e++) if (v[e] > v0) { v0 = v[e]; i0 = e; }
    int i1 = -1; float v1 = -1e30f;
#pragma unroll
    for (int e = 0; e < E_NUM; e++) if (e != i0 && v[e] > v1) { v1 = v[e]; i1 = e; }
    float g0 = 1.f / (1.f + expf(v1 - v0));
    float g1 = 1.f - g0;
    tidx[2 * t] = i0; tidx[2 * t + 1] = i1;
    tgate[2 * t] = g0; tgate[2 * t + 1] = g1;
    atomicAdd(cnt + i0, 1);
    atomicAdd(cnt + i1, 1);
  }
}

__global__ void k_prefix(const int* __restrict__ cnt, int* __restrict__ eoff,
                         int* __restrict__ cursor) {
  if (threadIdx.x == 0) {
    int a = 0;
    for (int e = 0; e < E_NUM; e++) { eoff[e] = a; cursor[e] = a; a += cnt[e]; }
    eoff[E_NUM] = a;
  }
}

__global__ void k_scatter(const int* __restrict__ tidx, const float* __restrict__ tgate,
                          int* __restrict__ cursor, int* __restrict__ ptok,
                          float* __restrict__ pgate) {
  int t = blockIdx.x * 256 + threadIdx.x;
#pragma unroll
  for (int k = 0; k < 2; k++) {
    int e = tidx[2 * t + k];
    int p = atomicAdd(cursor + e, 1);
    ptok[p] = t;
    pgate[p] = tgate[2 * t + k];
  }
}

// -- grouped GEMM, 128x128 tile, BK=32, depth-3 ring + counted vmcnt, 3 blk/CU
// 4 waves (256 thr), per-wave 64x64 (acc[4][4] = 64 AGPR); LDS 48 KB:
// [3 bufs][A/B][128 rows][32 bf16]; 64B rows of 4x16B segs, seg-swizzled
// slot[row][s] = data[row][s ^ ((row>>1)&3)] via pre-swizzled global source
// (R3/R5/R8: measured 0 bank conflicts). Per K-step (buf = kt%3):
// vmcnt(8) -> barrier -> 8 frag ds_reads -> lgkm0 -> barrier (WAR) ->
// STAGE(kt+3 into same buf) -> setprio(1) 16 MFMA setprio(0).
// 12 loads in flight/wave steady-state; never drain below 8 in main loop.
// NKT must be ≡ 2 (mod 3) and ≥ 8: GEMM1 K=1024 -> 32 ✓, GEMM2 K=4096 -> 128 ✓.
// MODE 1: A = xb gathered via ptok, out = relu(A@B^T + b1) -> Hbuf (bf16)
// MODE 2: A = Hbuf rows direct,   out = (A@B^T + b2)*gate atomicAdd-> Out
template <int KDIM, int NDIM, int MODE>
__global__ __launch_bounds__(256, 3) void k_gemm(
    const unsigned short* __restrict__ A, const unsigned short* __restrict__ Bt,
    const float* __restrict__ bias, const int* __restrict__ eoff,
    const int* __restrict__ ptok, const float* __restrict__ pgate,
    unsigned short* __restrict__ Hout, float* __restrict__ Out) {
  constexpr int NT = NDIM / 128;
  constexpr int MT_MAX = NPAIR / 128;
  constexpr int NKT = KDIM / 32;
  static_assert(NKT % 3 == 2 && NKT >= 8, "tail pattern requires NKT==2 mod 3");
  int nwg = gridDim.x;
  int bid = blockIdx.x;
  int tile = (bid & 7) * (nwg >> 3) + (bid >> 3);  // XCD chunk swizzle (nwg%8==0)
  int e = tile / (MT_MAX * NT);
  int rem = tile - e * (MT_MAX * NT);
  int mt = rem / NT;
  int nt = rem - mt * NT;
  int off = eoff[e];
  int cnt = eoff[e + 1] - off;
  int m0 = mt * 128;
  if (m0 >= cnt) return;

  __shared__ unsigned short lds[3][2][128 * 32];  // 48 KB

  int tid = threadIdx.x;
  int w = tid >> 6, lane = tid & 63;
  int wm = w >> 1, wn = w & 1;  // 2x2 wave grid; per-wave output 64x64

  // staging: chunk q = w*2+c covers rows q*16..q*16+15; lane -> row
  // q*16+(lane>>2), slot seg (lane&3); LDS offset q*512 + lane*8 shorts.
  // Pre-swizzled global seg: (lane&3) ^ ((row>>1)&3) = (lane&3)^((lane>>3)&3).
  int sseg = (lane & 3) ^ ((lane >> 3) & 3);
  const unsigned short* aSrc[2];
  const unsigned short* bSrc[2];
#pragma unroll
  for (int c = 0; c < 2; c++) {
    int q = w * 2 + c;
    int lrow = q * 16 + (lane >> 2);
    int arow = m0 + lrow;
    int ar = (arow < cnt) ? arow : (cnt - 1);
    size_t grow;
    if (MODE == 1) grow = (size_t)ptok[off + ar];
    else grow = (size_t)(off + ar);
    aSrc[c] = A + grow * KDIM + sseg * 8;
    int nrow = nt * 128 + q * 16 + (lane >> 2);
    bSrc[c] = Bt + (size_t)e * NDIM * KDIM + (size_t)nrow * KDIM + sseg * 8;
  }

  // frag reads: row = base + (lane&15); wanted seg = lane>>4;
  // slot seg' = (lane>>4) ^ ((row>>1)&3) = (lane>>4) ^ ((lane>>1)&3).
  int segp = (lane >> 4) ^ ((lane >> 1) & 3);
  f32x4 acc[4][4] = {};

#define STAGE(buf, k0)                                          \
  {                                                             \
    _Pragma("unroll")                                           \
    for (int c = 0; c < 2; c++) {                               \
      int q = w * 2 + c;                                        \
      gload16(aSrc[c] + (k0), &lds[buf][0][q * 512]);           \
      gload16(bSrc[c] + (k0), &lds[buf][1][q * 512]);           \
    }                                                           \
  }
#define NOSTG ((void)0)

#define STEP(buf, WAITC, STGC)                                              \
  {                                                                         \
    WAITC; BARRIER();                                                       \
    bf16x8 aF[4], bF[4];                                                    \
    _Pragma("unroll")                                                       \
    for (int m = 0; m < 4; m++) {                                           \
      int row = wm * 64 + m * 16 + (lane & 15);                             \
      aF[m] = *(const bf16x8*)&lds[buf][0][row * 32 + segp * 8];            \
    }                                                                       \
    _Pragma("unroll")                                                       \
    for (int n = 0; n < 4; n++) {                                           \
      int row = wn * 64 + n * 16 + (lane & 15);                             \
      bF[n] = *(const bf16x8*)&lds[buf][1][row * 32 + segp * 8];            \
    }                                                                       \
    LGKM0; BARRIER();                                                       \
    STGC;                                                                   \
    __builtin_amdgcn_s_setprio(1);                                          \
    _Pragma("unroll")                                                       \
    for (int m = 0; m < 4; m++)                                             \
      _Pragma("unroll")                                                     \
      for (int n = 0; n < 4; n++)                                           \
        acc[m][n] =                                                         \
            __builtin_amdgcn_mfma_f32_16x16x32_bf16(aF[m], bF[n], acc[m][n], 0, 0, 0); \
    __builtin_amdgcn_s_setprio(0);                                          \
  }

  // prologue: 3 K-steps in flight (12 loads per thread)
  STAGE(0, 0);
  STAGE(1, 32);
  STAGE(2, 64);

  // main: triples of steps, each staging kt+3 into its own (just-freed) buf
#pragma unroll 1
  for (int kt = 0; kt < NKT - 5; kt += 3) {
    STEP(0, VM8, STAGE(0, (kt + 3) * 32));
    STEP(1, VM8, STAGE(1, (kt + 4) * 32));
    STEP(2, VM8, STAGE(2, (kt + 5) * 32));
  }
  // tail: steps NKT-5 .. NKT-1 (NKT-5 ≡ 0 mod 3)
  STEP(0, VM8, STAGE(0, (NKT - 2) * 32));
  STEP(1, VM8, STAGE(1, (NKT - 1) * 32));
  STEP(2, VM8, NOSTG);
  STEP(0, VM4, NOSTG);
  STEP(1, VM0, NOSTG);

#undef STAGE
#undef NOSTG
#undef STEP

  // epilogue: C/D map col=lane&15, row=(lane>>4)*4+r
#pragma unroll
  for (int m = 0; m < 4; m++) {
    int lrowb = wm * 64 + m * 16 + (lane >> 4) * 4;
#pragma unroll
    for (int r = 0; r < 4; r++) {
      int arow = m0 + lrowb + r;
      if (arow < cnt) {
        if constexpr (MODE == 1) {
          size_t rowbase = (size_t)(off + arow) * NDIM;
#pragma unroll
          for (int n = 0; n < 4; n++) {
            int col = nt * 128 + wn * 64 + n * 16 + (lane & 15);
            float v = acc[m][n][r] + bias[e * NDIM + col];
            v = v > 0.f ? v : 0.f;
            Hout[rowbase + col] = f2bf(v);
          }
        } else {
          int tok = ptok[off + arow];
          float g = pgate[off + arow];
#pragma unroll
          for (int n = 0; n < 4; n++) {
            int col = nt * 128 + wn * 64 + n * 16 + (lane & 15);
            float v = (acc[m][n][r] + bias[e * NDIM + col]) * g;
            atomicAdd(Out + (size_t)tok * D_DIM + col, v);
          }
        }
      }
    }
  }
}

extern "C" void kernel_launch(void* const* d_in, const int* in_sizes, int n_in,
                              void* d_out, int out_size, void* d_ws, size_t ws_size,
                              hipStream_t stream) {
  const float* x  = (const float*)d_in[0];
  const float* wg = (const float*)d_in[1];
  const float* bg = (const float*)d_in[2];
  const float* w1 = (const float*)d_in[3];
  const float* b1 = (const float*)d_in[4];
  const float* w2 = (const float*)d_in[5];
  const float* b2 = (const float*)d_in[6];
  float* out = (float*)d_out;

  char* ws = (char*)d_ws;
  unsigned short* xb = (unsigned short*)ws;   ws += (size_t)B_TOK * D_DIM * 2;
  unsigned short* w1t = (unsigned short*)ws;  ws += (size_t)E_NUM * D_DIM * H_DIM * 2;
  unsigned short* w2t = (unsigned short*)ws;  ws += (size_t)E_NUM * D_DIM * H_DIM * 2;
  unsigned short* Hbuf = (unsigned short*)ws; ws += (size_t)NPAIR * H_DIM * 2;
  int* tidx = (int*)ws;    ws += (size_t)NPAIR * 4;
  float* tgate = (float*)ws; ws += (size_t)NPAIR * 4;
  int* ptok = (int*)ws;    ws += (size_t)NPAIR * 4;
  float* pgate = (float*)ws; ws += (size_t)NPAIR * 4;
  int* meta = (int*)ws;  // cnt[8] | eoff[9] | cursor[8]
  int* cnt = meta;
  int* eoff = meta + 8;
  int* cursor = meta + 17;

  hipMemsetAsync(meta, 0, 32 * sizeof(int), stream);
  hipMemsetAsync(out, 0, (size_t)out_size * sizeof(float), stream);

  k_convert_x<<<(B_TOK * D_DIM) / 1024, 256, 0, stream>>>(x, xb);
  k_prep_w<<<2 * E_NUM * 4096, dim3(32, 8), 0, stream>>>(w1, w2, w1t, w2t);
  k_router<<<B_TOK / 4, 256, 0, stream>>>(x, wg, bg, tidx, tgate, cnt);
  k_prefix<<<1, 64, 0, stream>>>(cnt, eoff, cursor);
  k_scatter<<<B_TOK / 256, 256, 0, stream>>>(tidx, tgate, cursor, ptok, pgate);
  k_gemm<D_DIM, H_DIM, 1><<<E_NUM * (NPAIR / 128) * (H_DIM / 128), 256, 0, stream>>>(
      xb, w1t, b1, eoff, ptok, pgate, Hbuf, nullptr);
  k_gemm<H_DIM, D_DIM, 2><<<E_NUM * (NPAIR / 128) * (D_DIM / 128), 256, 0, stream>>>(
      Hbuf, w2t, b2, eoff, ptok, pgate, nullptr, out);
}